// Round 1
// baseline (66.459 us; speedup 1.0000x reference)
//
#include <hip/hip_runtime.h>
#include <hip/hip_bf16.h>
#include <stdint.h>

typedef __bf16 bf16x8 __attribute__((ext_vector_type(8)));
typedef float f32x4 __attribute__((ext_vector_type(4)));
typedef unsigned short ushort8 __attribute__((ext_vector_type(8)));

#define NQ 8192
#define NP 4096
#define DD 512

__device__ inline unsigned short f32_to_bf16_rne(float f) {
  union { float f; uint32_t u; } v; v.f = f;
  uint32_t u = v.u;
  return (unsigned short)((u + 0x7fffu + ((u >> 16) & 1u)) >> 16);
}

// One wave per row: fp32 -> bf16 copy + fp32 sum-of-squares per row.
__global__ __launch_bounds__(256) void cvt_norms_kernel(
    const float* __restrict__ X, const float* __restrict__ Y,
    unsigned short* __restrict__ Xb, unsigned short* __restrict__ Yb,
    float* __restrict__ xsq, float* __restrict__ ysq) {
  const int wave = threadIdx.x >> 6;
  const int lane = threadIdx.x & 63;
  const int row = blockIdx.x * 4 + wave;  // 0..12287

  const float* src;
  unsigned short* dst;
  float* nrm;
  if (row < NQ) {
    src = X + (size_t)row * DD;
    dst = Xb + (size_t)row * DD;
    nrm = xsq + row;
  } else {
    const int r = row - NQ;
    src = Y + (size_t)r * DD;
    dst = Yb + (size_t)r * DD;
    nrm = ysq + r;
  }

  const float4 v0 = *(const float4*)(src + lane * 8);
  const float4 v1 = *(const float4*)(src + lane * 8 + 4);
  float s = v0.x * v0.x + v0.y * v0.y + v0.z * v0.z + v0.w * v0.w +
            v1.x * v1.x + v1.y * v1.y + v1.z * v1.z + v1.w * v1.w;

  ushort8 o;
  o[0] = f32_to_bf16_rne(v0.x);
  o[1] = f32_to_bf16_rne(v0.y);
  o[2] = f32_to_bf16_rne(v0.z);
  o[3] = f32_to_bf16_rne(v0.w);
  o[4] = f32_to_bf16_rne(v1.x);
  o[5] = f32_to_bf16_rne(v1.y);
  o[6] = f32_to_bf16_rne(v1.z);
  o[7] = f32_to_bf16_rne(v1.w);
  *(ushort8*)(dst + lane * 8) = o;

  #pragma unroll
  for (int off = 32; off; off >>= 1) s += __shfl_xor(s, off, 64);
  if (lane == 0) *nrm = s;
}

// 128x128 tile NT GEMM (C = Xb * Yb^T), BK=32, 4 waves (2x2), fused epilogue:
// out = (xsq[row] + ysq[col] - 2*dot) / 512
__global__ __launch_bounds__(256) void dist_gemm_kernel(
    const unsigned short* __restrict__ Xb, const unsigned short* __restrict__ Yb,
    const float* __restrict__ xsq, const float* __restrict__ ysq,
    float* __restrict__ out) {
  __shared__ unsigned short As[128 * 32];
  __shared__ unsigned short Bs[128 * 32];

  const int tid = threadIdx.x;
  const int wave = tid >> 6;
  const int lane = tid & 63;

  // XCD-aware swizzle: 2048 blocks, 8 XCDs, 256 contiguous wgids per XCD.
  const int bid = blockIdx.x;
  const int wgid = (bid & 7) * 256 + (bid >> 3);
  const int tileN = wgid & 31;  // 32 N-tiles
  const int tileM = wgid >> 5;  // 64 M-tiles
  const int brow = tileM * 128;
  const int bcol = tileN * 128;

  const int wr = wave >> 1, wc = wave & 1;
  const int lrow = lane >> 2;          // staging: row within 16-row chunk
  const int lcol = (lane & 3) * 8;     // staging: col (8 bf16 = 16 B)
  const int fr = lane & 15, fq = lane >> 4;  // fragment lane decomposition

  f32x4 acc[4][4] = {};

  for (int kt = 0; kt < DD; kt += 32) {
    #pragma unroll
    for (int s = 0; s < 2; ++s) {
      const int c = wave * 2 + s;  // chunk 0..7; 16 rows per chunk
      const unsigned short* ga =
          Xb + (size_t)(brow + c * 16 + lrow) * DD + kt + lcol;
      const unsigned short* gb =
          Yb + (size_t)(bcol + c * 16 + lrow) * DD + kt + lcol;
      __builtin_amdgcn_global_load_lds(
          (const __attribute__((address_space(1))) void*)ga,
          (__attribute__((address_space(3))) void*)(As + c * 512), 16, 0, 0);
      __builtin_amdgcn_global_load_lds(
          (const __attribute__((address_space(1))) void*)gb,
          (__attribute__((address_space(3))) void*)(Bs + c * 512), 16, 0, 0);
    }
    __syncthreads();

    bf16x8 a[4], b[4];
    #pragma unroll
    for (int m = 0; m < 4; ++m)
      a[m] = *(const bf16x8*)(As + (wr * 64 + m * 16 + fr) * 32 + fq * 8);
    #pragma unroll
    for (int n = 0; n < 4; ++n)
      b[n] = *(const bf16x8*)(Bs + (wc * 64 + n * 16 + fr) * 32 + fq * 8);

    #pragma unroll
    for (int m = 0; m < 4; ++m)
      #pragma unroll
      for (int n = 0; n < 4; ++n)
        acc[m][n] = __builtin_amdgcn_mfma_f32_16x16x32_bf16(a[m], b[n],
                                                            acc[m][n], 0, 0, 0);
    __syncthreads();
  }

  // Epilogue: out[row][col] = (xsq[row] + ysq[col] - 2*acc) * (1/512)
  float ysv[4];
  #pragma unroll
  for (int n = 0; n < 4; ++n) ysv[n] = ysq[bcol + wc * 64 + n * 16 + fr];

  #pragma unroll
  for (int m = 0; m < 4; ++m) {
    float xsv[4];
    #pragma unroll
    for (int r = 0; r < 4; ++r)
      xsv[r] = xsq[brow + wr * 64 + m * 16 + fq * 4 + r];
    #pragma unroll
    for (int n = 0; n < 4; ++n) {
      const int col = bcol + wc * 64 + n * 16 + fr;
      #pragma unroll
      for (int r = 0; r < 4; ++r) {
        const int row = brow + wr * 64 + m * 16 + fq * 4 + r;
        out[(size_t)row * NP + col] =
            (xsv[r] + ysv[n] - 2.0f * acc[m][n][r]) * (1.0f / 512.0f);
      }
    }
  }
}

extern "C" void kernel_launch(void* const* d_in, const int* in_sizes, int n_in,
                              void* d_out, int out_size, void* d_ws, size_t ws_size,
                              hipStream_t stream) {
  const float* X = (const float*)d_in[0];  // z_queries (8192, 512)
  const float* Y = (const float*)d_in[1];  // class_prototypes (4096, 512)
  float* out = (float*)d_out;              // (8192, 4096)

  unsigned short* Xb = (unsigned short*)d_ws;               // 8192*512 bf16
  unsigned short* Yb = Xb + (size_t)NQ * DD;                // 4096*512 bf16
  float* xsq = (float*)(Yb + (size_t)NP * DD);              // 8192 f32
  float* ysq = xsq + NQ;                                    // 4096 f32

  cvt_norms_kernel<<<(NQ + NP) / 4, 256, 0, stream>>>(X, Y, Xb, Yb, xsq, ysq);
  dist_gemm_kernel<<<(NQ / 128) * (NP / 128), 256, 0, stream>>>(Xb, Yb, xsq,
                                                                ysq, out);
}

// Round 2
// 60.736 us; speedup vs baseline: 1.0942x; 1.0942x over previous
//
#include <hip/hip_runtime.h>
#include <hip/hip_bf16.h>
#include <stdint.h>

typedef __bf16 bf16x8 __attribute__((ext_vector_type(8)));
typedef float f32x4 __attribute__((ext_vector_type(4)));
typedef unsigned short ushort8 __attribute__((ext_vector_type(8)));

#define NQ 8192
#define NP 4096
#define DD 512
#define NTILES 8  // DD / 64

__device__ inline unsigned short f32_to_bf16_rne(float f) {
  union { float f; uint32_t u; } v; v.f = f;
  uint32_t u = v.u;
  return (unsigned short)((u + 0x7fffu + ((u >> 16) & 1u)) >> 16);
}

// One wave per row: fp32 -> bf16 copy + fp32 sum-of-squares per row.
__global__ __launch_bounds__(256) void cvt_norms_kernel(
    const float* __restrict__ X, const float* __restrict__ Y,
    unsigned short* __restrict__ Xb, unsigned short* __restrict__ Yb,
    float* __restrict__ xsq, float* __restrict__ ysq) {
  const int wave = threadIdx.x >> 6;
  const int lane = threadIdx.x & 63;
  const int row = blockIdx.x * 4 + wave;  // 0..12287

  const float* src;
  unsigned short* dst;
  float* nrm;
  if (row < NQ) {
    src = X + (size_t)row * DD;
    dst = Xb + (size_t)row * DD;
    nrm = xsq + row;
  } else {
    const int r = row - NQ;
    src = Y + (size_t)r * DD;
    dst = Yb + (size_t)r * DD;
    nrm = ysq + r;
  }

  const float4 v0 = *(const float4*)(src + lane * 8);
  const float4 v1 = *(const float4*)(src + lane * 8 + 4);
  float s = v0.x * v0.x + v0.y * v0.y + v0.z * v0.z + v0.w * v0.w +
            v1.x * v1.x + v1.y * v1.y + v1.z * v1.z + v1.w * v1.w;

  ushort8 o;
  o[0] = f32_to_bf16_rne(v0.x);
  o[1] = f32_to_bf16_rne(v0.y);
  o[2] = f32_to_bf16_rne(v0.z);
  o[3] = f32_to_bf16_rne(v0.w);
  o[4] = f32_to_bf16_rne(v1.x);
  o[5] = f32_to_bf16_rne(v1.y);
  o[6] = f32_to_bf16_rne(v1.z);
  o[7] = f32_to_bf16_rne(v1.w);
  *(ushort8*)(dst + lane * 8) = o;

  #pragma unroll
  for (int off = 32; off; off >>= 1) s += __shfl_xor(s, off, 64);
  if (lane == 0) *nrm = s;
}

// ---------------------------------------------------------------------------
// 256x256-tile NT GEMM, BK=64, 8 waves (2Mx4N), 8-phase schedule with counted
// vmcnt(10), swizzled LDS, setprio around MFMA. Fused distance epilogue.
//
// LDS layout (128 KiB): A: [buf][khalf][256 rows][32 cols], 16 KiB per
// (buf,khalf) region; B same at +64 KiB. Swizzle: 16B-chunk index within a
// 64B row XORed with (row>>1)&3 (involution; applied inverse on global src).
//
// Half-tile stage schedule per group g (computes K-tile g from buf g&1):
//   Ph1: stage B-k1(g+1)  Ph2: stage A-k0(g+2)  Ph3: stage B-k0(g+2)
//   Ph4: stage A-k1(g+2)       (tile index mod 8; 2 loads/wave each)
// vmcnt(10) = 5 half-tiles in flight, at Ph2 (covers Ph3 reads) and Ph4
// (covers next group's Ph1 reads); prologue stages 7 half-tiles + vmcnt(10).
// ---------------------------------------------------------------------------
__global__ __launch_bounds__(512, 2) void dist_gemm_kernel(
    const unsigned short* __restrict__ Xb, const unsigned short* __restrict__ Yb,
    const float* __restrict__ xsq, const float* __restrict__ ysq,
    float* __restrict__ out) {
  __shared__ unsigned char lds[131072];

  const int tid = threadIdx.x;
  const int wave = tid >> 6;
  const int lane = tid & 63;
  const int fr = lane & 15, fq = lane >> 4;
  const int wr = wave >> 2;  // 0..1, owns rows wr*128..+128
  const int wc = wave & 3;   // 0..3, owns cols wc*64..+64

  // XCD swizzle (512 blocks, 64 per XCD); tileN fastest within an XCD chunk.
  const int bid = blockIdx.x;
  const int wgid = (bid & 7) * 64 + (bid >> 3);
  const int tileN = wgid & 15;
  const int tileM = wgid >> 4;
  const int brow = tileM * 256;
  const int bcol = tileN * 256;

  // stage one 16KB half-tile (khalf ks of K-tile t) into buffer `buf`.
  auto stage = [&](int buf, int t, int ks, bool isA) {
    const unsigned short* base =
        isA ? (Xb + (size_t)brow * DD) : (Yb + (size_t)bcol * DD);
    const unsigned ldsbase =
        (isA ? 0u : 65536u) + (unsigned)buf * 32768u + (unsigned)ks * 16384u;
    const int tt = t & 7;
    #pragma unroll
    for (int i = 0; i < 2; ++i) {
      const unsigned P0 = (unsigned)(wave * 2 + i) * 1024u;  // wave-uniform
      const unsigned P = P0 + (unsigned)lane * 16u;          // this lane's dst
      const unsigned L = P ^ (((P >> 7) & 3u) << 4);         // inverse swizzle
      const unsigned row = L >> 6;
      const unsigned col = (L & 63u) >> 1;
      const unsigned short* src = base + (size_t)row * DD + tt * 64 + ks * 32 + col;
      __builtin_amdgcn_global_load_lds(
          (const __attribute__((address_space(1))) void*)src,
          (__attribute__((address_space(3))) void*)(lds + ldsbase + P0), 16, 0, 0);
    }
  };

  // per-thread swizzled chunk offset for ds_read fragments
  const unsigned cswz = (unsigned)((fq ^ ((fr >> 1) & 3)) << 4);
  const unsigned rA = (unsigned)((wr * 128 + fr) * 64) + cswz;  // + m*1024 + ks*16384
  const unsigned rB = (unsigned)((wc * 64 + fr) * 64) + cswz;   // + n*1024 + ks*16384

  f32x4 acc[8][4] = {};
  bf16x8 a[8], b0, b1;

  // ---- prologue: A-k0(0) B-k0(0) A-k1(0) B-k1(0) A-k0(1) B-k0(1) A-k1(1)
  stage(0, 0, 0, true);
  stage(0, 0, 0, false);
  stage(0, 0, 1, true);
  stage(0, 0, 1, false);
  stage(1, 1, 0, true);
  stage(1, 1, 0, false);
  stage(1, 1, 1, true);
  asm volatile("s_waitcnt vmcnt(10)" ::: "memory");
  __builtin_amdgcn_s_barrier();

  #pragma unroll 2
  for (int g = 0; g < NTILES; ++g) {
    const int buf = g & 1;
    const unsigned Ab = (unsigned)buf * 32768u;
    const unsigned Bb = 65536u + (unsigned)buf * 32768u;

    // ---- Phase 1: ks=0, n-half 0 ----
    #pragma unroll
    for (int m = 0; m < 8; ++m)
      a[m] = *(const bf16x8*)(lds + Ab + rA + (unsigned)m * 1024u);
    b0 = *(const bf16x8*)(lds + Bb + rB + 0u);
    b1 = *(const bf16x8*)(lds + Bb + rB + 1024u);
    stage(buf ^ 1, g + 1, 1, false);  // B-k1(g+1)
    __builtin_amdgcn_s_barrier();
    asm volatile("s_waitcnt lgkmcnt(0)" ::: "memory");
    __builtin_amdgcn_sched_barrier(0);
    __builtin_amdgcn_s_setprio(1);
    #pragma unroll
    for (int m = 0; m < 8; ++m) {
      acc[m][0] = __builtin_amdgcn_mfma_f32_16x16x32_bf16(a[m], b0, acc[m][0], 0, 0, 0);
      acc[m][1] = __builtin_amdgcn_mfma_f32_16x16x32_bf16(a[m], b1, acc[m][1], 0, 0, 0);
    }
    __builtin_amdgcn_s_setprio(0);
    __builtin_amdgcn_s_barrier();

    // ---- Phase 2: ks=0, n-half 1 ----
    b0 = *(const bf16x8*)(lds + Bb + rB + 2048u);
    b1 = *(const bf16x8*)(lds + Bb + rB + 3072u);
    stage(buf, g + 2, 0, true);  // A-k0(g+2)
    asm volatile("s_waitcnt vmcnt(10)" ::: "memory");
    __builtin_amdgcn_s_barrier();
    asm volatile("s_waitcnt lgkmcnt(0)" ::: "memory");
    __builtin_amdgcn_sched_barrier(0);
    __builtin_amdgcn_s_setprio(1);
    #pragma unroll
    for (int m = 0; m < 8; ++m) {
      acc[m][2] = __builtin_amdgcn_mfma_f32_16x16x32_bf16(a[m], b0, acc[m][2], 0, 0, 0);
      acc[m][3] = __builtin_amdgcn_mfma_f32_16x16x32_bf16(a[m], b1, acc[m][3], 0, 0, 0);
    }
    __builtin_amdgcn_s_setprio(0);
    __builtin_amdgcn_s_barrier();

    // ---- Phase 3: ks=1, n-half 0 ----
    #pragma unroll
    for (int m = 0; m < 8; ++m)
      a[m] = *(const bf16x8*)(lds + Ab + 16384u + rA + (unsigned)m * 1024u);
    b0 = *(const bf16x8*)(lds + Bb + 16384u + rB + 0u);
    b1 = *(const bf16x8*)(lds + Bb + 16384u + rB + 1024u);
    stage(buf, g + 2, 0, false);  // B-k0(g+2)
    __builtin_amdgcn_s_barrier();
    asm volatile("s_waitcnt lgkmcnt(0)" ::: "memory");
    __builtin_amdgcn_sched_barrier(0);
    __builtin_amdgcn_s_setprio(1);
    #pragma unroll
    for (int m = 0; m < 8; ++m) {
      acc[m][0] = __builtin_amdgcn_mfma_f32_16x16x32_bf16(a[m], b0, acc[m][0], 0, 0, 0);
      acc[m][1] = __builtin_amdgcn_mfma_f32_16x16x32_bf16(a[m], b1, acc[m][1], 0, 0, 0);
    }
    __builtin_amdgcn_s_setprio(0);
    __builtin_amdgcn_s_barrier();

    // ---- Phase 4: ks=1, n-half 1 ----
    b0 = *(const bf16x8*)(lds + Bb + 16384u + rB + 2048u);
    b1 = *(const bf16x8*)(lds + Bb + 16384u + rB + 3072u);
    stage(buf, g + 2, 1, true);  // A-k1(g+2)
    asm volatile("s_waitcnt vmcnt(10)" ::: "memory");
    __builtin_amdgcn_s_barrier();
    asm volatile("s_waitcnt lgkmcnt(0)" ::: "memory");
    __builtin_amdgcn_sched_barrier(0);
    __builtin_amdgcn_s_setprio(1);
    #pragma unroll
    for (int m = 0; m < 8; ++m) {
      acc[m][2] = __builtin_amdgcn_mfma_f32_16x16x32_bf16(a[m], b0, acc[m][2], 0, 0, 0);
      acc[m][3] = __builtin_amdgcn_mfma_f32_16x16x32_bf16(a[m], b1, acc[m][3], 0, 0, 0);
    }
    __builtin_amdgcn_s_setprio(0);
    __builtin_amdgcn_s_barrier();
  }

  // ---- epilogue: out[row][col] = (xsq[row] + ysq[col] - 2*acc) / 512 ----
  float ysv[4];
  #pragma unroll
  for (int n = 0; n < 4; ++n) ysv[n] = ysq[bcol + wc * 64 + n * 16 + fr];

  #pragma unroll
  for (int m = 0; m < 8; ++m) {
    const int rowb = brow + wr * 128 + m * 16 + fq * 4;
    float xsv[4];
    #pragma unroll
    for (int r = 0; r < 4; ++r) xsv[r] = xsq[rowb + r];
    #pragma unroll
    for (int n = 0; n < 4; ++n) {
      const int col = bcol + wc * 64 + n * 16 + fr;
      #pragma unroll
      for (int r = 0; r < 4; ++r) {
        out[(size_t)(rowb + r) * NP + col] =
            (xsv[r] + ysv[n] - 2.0f * acc[m][n][r]) * (1.0f / 512.0f);
      }
    }
  }
}

extern "C" void kernel_launch(void* const* d_in, const int* in_sizes, int n_in,
                              void* d_out, int out_size, void* d_ws, size_t ws_size,
                              hipStream_t stream) {
  const float* X = (const float*)d_in[0];  // z_queries (8192, 512)
  const float* Y = (const float*)d_in[1];  // class_prototypes (4096, 512)
  float* out = (float*)d_out;              // (8192, 4096)

  unsigned short* Xb = (unsigned short*)d_ws;   // 8192*512 bf16
  unsigned short* Yb = Xb + (size_t)NQ * DD;    // 4096*512 bf16
  float* xsq = (float*)(Yb + (size_t)NP * DD);  // 8192 f32
  float* ysq = xsq + NQ;                        // 4096 f32

  cvt_norms_kernel<<<(NQ + NP) / 4, 256, 0, stream>>>(X, Y, Xb, Yb, xsq, ysq);
  dist_gemm_kernel<<<(NQ / 256) * (NP / 256), 512, 0, stream>>>(Xb, Yb, xsq,
                                                                ysq, out);
}